// Round 5
// baseline (174.950 us; speedup 1.0000x reference)
//
#include <hip/hip_runtime.h>
#include <math.h>

// Problem constants (fixed by setup_inputs)
#define W_ 192
#define H_ 192
#define D_ 160
#define B_ 2
#define XT 32             // x outputs per block (2 per thread)
#define YT 16             // y outputs per block
#define HX 36             // XT + 4
#define HY 20             // YT + 4
#define CHUNK 10          // z outputs per block
#define PLANES (CHUNK + 4)
#define GXD 6
#define GYD 12
#define GZD 32            // 16 z-chunks x 2 batches
#define NBLK (GXD * GYD * GZD)   // 2304
#define NTOT 11796480.0f  // 2*1*160*192*192

struct Q2 { float2 s, t, a, b, c; };  // {Σs, Σt, Σs², Σt², Σst} for 2 x-columns

__device__ __forceinline__ float2 f2add(float2 u, float2 v) { return make_float2(u.x + v.x, u.y + v.y); }
__device__ __forceinline__ float2 f2sub(float2 u, float2 v) { return make_float2(u.x - v.x, u.y - v.y); }

__global__ __launch_bounds__(256) void lncc_main(const float* __restrict__ src,
                                                 const float* __restrict__ tgt,
                                                 float* __restrict__ partial) {
    // raw: interleaved (s,t) pairs — float4 = {s(2k),t(2k),s(2k+1),t(2k+1)} —
    // double-buffered for the prefetch pipeline. rowsums single-buffered
    // (2 barriers/plane), float2 = both x-columns of one pair-thread.
    __shared__ float4 raw[2][HY][19];       // 19 float4 covers 38 x-slots (need 36)
    __shared__ float2 rsS [HY][17];
    __shared__ float2 rsT [HY][17];
    __shared__ float2 rsS2[HY][17];
    __shared__ float2 rsT2[HY][17];
    __shared__ float2 rsST[HY][17];
    __shared__ float wsum[4];

    const int tx  = threadIdx.x, ty = threadIdx.y;   // 16 x 16
    const int tid = ty * 16 + tx;
    const int bz  = blockIdx.z;
    const int b   = bz >> 4;                 // 16 z-chunks per batch
    const int z0  = (bz & 15) * CHUNK;
    const int bx0 = blockIdx.x * XT - 2;     // even -> float2-aligned columns
    const int by0 = blockIdx.y * YT - 2;

    // ---- staging decode: 360 float2-pair slots, thread gets slot tid (+256 if tid<104)
    const int  r0s = tid / 18,          c0s = tid - r0s * 18;
    const int  s1  = 256 + tid;
    const int  r1s = s1 / 18,           c1s = s1 - r1s * 18;
    const bool has2 = (tid < 104);

    auto load_slot = [&](int r, int c, int zp, float2& vS, float2& vT) {
        vS = make_float2(0.f, 0.f); vT = make_float2(0.f, 0.f);
        const int gx = bx0 + 2 * c, gy = by0 + r;
        if ((unsigned)zp < (unsigned)D_ && (unsigned)gy < (unsigned)H_ &&
            (unsigned)gx < (unsigned)W_) {
            const size_t off = (size_t)(b * D_ + zp) * (size_t)(H_ * W_)
                             + (size_t)gy * W_ + (size_t)gx;
            vS = *(const float2*)(src + off);
            vT = *(const float2*)(tgt + off);
        }
    };
    auto store_slot = [&](int bf, int r, int c, float2 vS, float2 vT) {
        raw[bf][r][c] = make_float4(vS.x, vT.x, vS.y, vT.y);
    };

    // ---- phase1: pair p -> rowsums for output cols x=2px, 2px+1 at halo row r
    auto do_pair = [&](int p, int bf) {
        const int r = p >> 4, px = p & 15;
        float4 A = raw[bf][r][px];
        float4 Bv = raw[bf][r][px + 1];
        float4 C = raw[bf][r][px + 2];
        float s0 = A.x,  t0 = A.y,  sx1 = A.z,  tx1 = A.w;
        float s2 = Bv.x, t2 = Bv.y, s3 = Bv.z,  t3 = Bv.w;
        float s4 = C.x,  t4 = C.y,  s5 = C.z,   t5 = C.w;
        float S0 = s0 + sx1 + s2 + s3 + s4;
        float T0 = t0 + tx1 + t2 + t3 + t4;
        float A0 = fmaf(s4, s4, fmaf(s3, s3, fmaf(s2, s2, fmaf(sx1, sx1, s0 * s0))));
        float B0 = fmaf(t4, t4, fmaf(t3, t3, fmaf(t2, t2, fmaf(tx1, tx1, t0 * t0))));
        float C0 = fmaf(s4, t4, fmaf(s3, t3, fmaf(s2, t2, fmaf(sx1, tx1, s0 * t0))));
        float S1 = S0 - s0 + s5;
        float T1 = T0 - t0 + t5;
        float A1 = fmaf(s5, s5, fmaf(-s0, s0, A0));
        float B1 = fmaf(t5, t5, fmaf(-t0, t0, B0));
        float C1 = fmaf(s5, t5, fmaf(-s0, t0, C0));
        rsS [r][px] = make_float2(S0, S1);
        rsT [r][px] = make_float2(T0, T1);
        rsS2[r][px] = make_float2(A0, A1);
        rsT2[r][px] = make_float2(B0, B1);
        rsST[r][px] = make_float2(C0, C1);
    };

    // z-ring as named structs rotated by assignment (arrays -> scratch; r2 lesson)
    Q2 q0 = {}, q1 = {}, q2 = {}, q3 = {}, q4 = {};
    Q2 zs = {};
    float2 lsum = make_float2(0.f, 0.f);

    // ---- prologue: stage plane 0 (zp = z0-2) into raw[0]
    {
        float2 aS, aT, bS, bT;
        load_slot(r0s, c0s, z0 - 2, aS, aT);
        if (has2) load_slot(r1s, c1s, z0 - 2, bS, bT);
        store_slot(0, r0s, c0s, aS, aT);
        if (has2) store_slot(0, r1s, c1s, bS, bT);
    }

    for (int i = 0; i < PLANES; ++i) {
        const int buf = i & 1;
        __syncthreads();   // raw[buf] writes visible; prev phase2 rs reads done
        // -- prefetch plane i+1 into registers (consumed after phase2) --
        float2 aS, aT, bS, bT;
        const bool haveNext = (i + 1 < PLANES);
        if (haveNext) {
            load_slot(r0s, c0s, z0 - 1 + i, aS, aT);
            if (has2) load_slot(r1s, c1s, z0 - 1 + i, bS, bT);
        }
        // -- phase1: raw[buf] -> rowsums --
        do_pair(tid, buf);
        if (tid < 64) do_pair(256 + tid, buf);
        __syncthreads();   // rs visible
        // -- phase2: y-window + z sliding window + epilogue --
        {
            float2 yS = make_float2(0.f, 0.f), yT = yS, yA = yS, yB = yS, yC = yS;
            #pragma unroll
            for (int dy = 0; dy < 5; ++dy) {
                yS = f2add(yS, rsS [ty + dy][tx]);
                yT = f2add(yT, rsT [ty + dy][tx]);
                yA = f2add(yA, rsS2[ty + dy][tx]);
                yB = f2add(yB, rsT2[ty + dy][tx]);
                yC = f2add(yC, rsST[ty + dy][tx]);
            }
            zs.s = f2add(zs.s, f2sub(yS, q0.s));
            zs.t = f2add(zs.t, f2sub(yT, q0.t));
            zs.a = f2add(zs.a, f2sub(yA, q0.a));
            zs.b = f2add(zs.b, f2sub(yB, q0.b));
            zs.c = f2add(zs.c, f2sub(yC, q0.c));
            q0 = q1; q1 = q2; q2 = q3; q3 = q4;
            q4.s = yS; q4.t = yT; q4.a = yA; q4.b = yB; q4.c = yC;
            if (i >= 4) {
                const float inv = 1.0f / 125.0f;
                {   // column x = 2tx
                    float ms = zs.s.x * inv, mt = zs.t.x * inv;
                    float vs = fmaf(-ms, ms, zs.a.x * inv);
                    float vt = fmaf(-mt, mt, zs.b.x * inv);
                    float cr = fmaf(-ms, mt, zs.c.x * inv);
                    float den = fmaf(vs, vt, 1e-5f);
                    lsum.x = fmaf(cr * cr, __builtin_amdgcn_rcpf(den), lsum.x);
                }
                {   // column x = 2tx+1
                    float ms = zs.s.y * inv, mt = zs.t.y * inv;
                    float vs = fmaf(-ms, ms, zs.a.y * inv);
                    float vt = fmaf(-mt, mt, zs.b.y * inv);
                    float cr = fmaf(-ms, mt, zs.c.y * inv);
                    float den = fmaf(vs, vt, 1e-5f);
                    lsum.y = fmaf(cr * cr, __builtin_amdgcn_rcpf(den), lsum.y);
                }
            }
        }
        // -- write prefetched plane into the other raw buffer --
        if (haveNext) {
            store_slot(buf ^ 1, r0s, c0s, aS, aT);
            if (has2) store_slot(buf ^ 1, r1s, c1s, bS, bT);
        }
    }

    // block reduction -> per-block partial
    float ls = lsum.x + lsum.y;
    #pragma unroll
    for (int off = 32; off > 0; off >>= 1)
        ls += __shfl_down(ls, off, 64);
    if ((tid & 63) == 0) wsum[tid >> 6] = ls;
    __syncthreads();
    if (tid == 0) {
        const int bid = (blockIdx.z * GYD + blockIdx.y) * GXD + blockIdx.x;
        partial[bid] = wsum[0] + wsum[1] + wsum[2] + wsum[3];
    }
}

__global__ __launch_bounds__(256) void lncc_finalize(const float* __restrict__ partial,
                                                     float* __restrict__ out) {
    __shared__ float ws[4];
    const int t = threadIdx.x;
    float s = 0.0f;
    for (int i = t; i < NBLK; i += 256) s += partial[i];
    #pragma unroll
    for (int off = 32; off > 0; off >>= 1) s += __shfl_down(s, off, 64);
    if ((t & 63) == 0) ws[t >> 6] = s;
    __syncthreads();
    if (t == 0) {
        float tot = ws[0] + ws[1] + ws[2] + ws[3];
        float loss = 1.0f - tot * (1.0f / NTOT);
        if (isnan(loss) || isinf(loss)) loss = 1.0f;
        *out = loss;
    }
}

extern "C" void kernel_launch(void* const* d_in, const int* in_sizes, int n_in,
                              void* d_out, int out_size, void* d_ws, size_t ws_size,
                              hipStream_t stream) {
    const float* src = (const float*)d_in[0];
    const float* tgt = (const float*)d_in[1];
    float* out = (float*)d_out;
    float* partial = (float*)d_ws;   // NBLK floats of scratch

    dim3 grid(GXD, GYD, GZD);        // 6 x 12 x 32 = 2304 blocks
    dim3 block(16, 16, 1);
    lncc_main<<<grid, block, 0, stream>>>(src, tgt, partial);
    lncc_finalize<<<dim3(1), dim3(256), 0, stream>>>(partial, out);
}